// Round 18
// baseline (264.131 us; speedup 1.0000x reference)
//
#include <hip/hip_runtime.h>

// RegressorHybrid: per-edge 2x MLP (128->64->64->32->1, lrelu 0.01), E=2M, H=64.
// Round 24: 3-stream skew pipeline. R23 (R19+grid512, 179.5us main, best):
// MFMA 28 + VALU 37 = 65% issue-busy, 35% stall at 2 waves/SIMD - NOT a
// roofline. R18 proved skew(+1 phase) = +7% by breaking the L1->L2 dep;
// the L2->L3->L4 chain is still serial. Fix: three independent streams per
// iteration: A = layer1(T+1) [16 MFMA from Gcur], B = layer2(T) [from
// carried accP], C = layers3-4+store(T-1) [from carried acc2P]. Scheduler
// interleaves 28 MFMAs + repacks across chains. Delta vs R23: carry acc2P
// (+16 regs), store delayed 1 iter (flag; iter0 stream C runs on zeros,
// store suppressed), epilogue flush for the last tile. Memory pipeline
// verbatim. Numerics identical (same op order per tile).
// Register audit (+30 honesty margin): ~200 unified < 256 two-wave budget;
// NOT the R13/R14 spill regime (~240+); NO occupancy request (R7/R8/R20
// law: any waves/EU request near demand spill-chases - proven 3x).
// Kept: ALL weights+biases in LDS (38912B; LDS reads non-binding: R10/R17),
// w4 in regs, in-place gather (Gcur dead after B1n cast), warm depth 2 +
// eidx I1-I3 rotating prefetch (warm law R1-R5: one warm b128 covers the
// tile's 64 lines, 1 fill each; consume gathers hit L1/L2; FETCH 184MB =
// raw), setprio(1) compute / 0 memory, stride-8 pairing (m=(bid>>3)&1)
// for L2 warm dedup across MLPs, grid 512 (exactly resident at 2 blk/CU).
// h1-precompute closed (R21/R22: per-MLP tables = 2x gather traffic).
// MFMA layouts: A[m=lane&15][k=(lane>>4)*8+j], B[k=(lane>>4)*8+j][n=lane&15],
//               C/D[row=4*(lane>>4)+reg][col=lane&15].

typedef _Float16 half8  __attribute__((ext_vector_type(8)));
typedef _Float16 half4v __attribute__((ext_vector_type(4)));
typedef _Float16 half2v __attribute__((ext_vector_type(2)));
typedef float    float4v __attribute__((ext_vector_type(4)));

#define MLP_W_BYTES 28672          // w1f 16384 + w2f 8192 + w3f 4096
#define MLP_R_BYTES 12288          // w4f 2048 + b1f 4096 + b2f 4096 + b3f 2048
#define W1F 0
#define W2F 16384
#define W3F 24576
#define LB1F 28672                 // LDS offsets for biases
#define LB2F 32768
#define LB3F 36864
#define LDS_TOTAL 38912            // w1f+w2f+w3f 28672 + b1f 4096 + b2f 4096 + b3f 2048
#define WS_REST_OFF 57344
#define WS_X16_OFF  81920

__device__ __forceinline__ float lrelu(float x) { return fmaxf(x, 0.01f * x); }

__device__ __forceinline__ int uperm(int k) {
    return 16 * (2 * ((k >> 2) & 1) + ((k >> 5) & 1)) + 4 * ((k >> 3) & 3) + (k & 3);
}

// ---- pack one MLP's weights/biases into per-lane fragment order ----
__global__ void prep_frags(const float* __restrict__ w1, const float* __restrict__ b1,
                           const float* __restrict__ w2, const float* __restrict__ b2,
                           const float* __restrict__ w3, const float* __restrict__ b3,
                           const float* __restrict__ w4,
                           unsigned char* __restrict__ dstL,
                           unsigned char* __restrict__ dstR)
{
    int idx = blockIdx.x * blockDim.x + threadIdx.x;
    if (idx < 8192) {                      // w1f: [16 frags][64 lanes][8 f16]
        int L = (idx >> 3) & 63, j = idx & 7, f = idx >> 9;
        int q = L >> 4, mm = L & 15, t = f >> 2, s = f & 3;
        int k = 32 * s + 8 * q + j;
        ((_Float16*)(dstL + W1F))[idx] = (_Float16)w1[k * 64 + 16 * t + mm];
        return;
    }
    idx -= 8192;
    if (idx < 4096) {                      // w2f: [8][64][8]
        int L = (idx >> 3) & 63, j = idx & 7, f = idx >> 9;
        int q = L >> 4, mm = L & 15, t = f >> 1, s = f & 1;
        int u = uperm(32 * s + 8 * q + j);
        ((_Float16*)(dstL + W2F))[idx] = (_Float16)w2[u * 64 + 16 * t + mm];
        return;
    }
    idx -= 4096;
    if (idx < 2048) {                      // w3f: [4][64][8]
        int L = (idx >> 3) & 63, j = idx & 7, f = idx >> 9;
        int q = L >> 4, mm = L & 15, t = f >> 1, s = f & 1;
        int u = uperm(32 * s + 8 * q + j);
        ((_Float16*)(dstL + W3F))[idx] = (_Float16)w3[u * 32 + 16 * t + mm];
        return;
    }
    idx -= 2048;
    if (idx < 512) {                       // w4f
        int L = idx >> 3, j = idx & 7;
        int q = L >> 4, t = j >> 2, r = j & 3;
        ((float*)(dstR + 0))[idx] = w4[16 * t + 4 * q + r];
        return;
    }
    idx -= 512;
    if (idx < 1024) {                      // b1f
        int t = idx >> 8, L = (idx >> 2) & 63, r = idx & 3, q = L >> 4;
        ((float*)(dstR + 2048))[idx] = b1[16 * t + 4 * q + r];
        return;
    }
    idx -= 1024;
    if (idx < 1024) {                      // b2f
        int t = idx >> 8, L = (idx >> 2) & 63, r = idx & 3, q = L >> 4;
        ((float*)(dstR + 6144))[idx] = b2[16 * t + 4 * q + r];
        return;
    }
    idx -= 1024;
    if (idx < 512) {                       // b3f
        int t = idx >> 8, L = (idx >> 2) & 63, r = idx & 3, q = L >> 4;
        ((float*)(dstR + 10240))[idx] = b3[16 * t + 4 * q + r];
        return;
    }
}

// ---- convert node tables fp32 -> f16 ----
__global__ void prep_nodes(const float* __restrict__ xs, const float* __restrict__ xd,
                           _Float16* __restrict__ os, _Float16* __restrict__ od, int n4)
{
    int stride = gridDim.x * blockDim.x;
    for (int i = blockIdx.x * blockDim.x + threadIdx.x; i < n4; i += stride) {
        float4v a = ((const float4v*)xs)[i];
        float4v b = ((const float4v*)xd)[i];
        half4v ha, hb;
#pragma unroll
        for (int j = 0; j < 4; ++j) { ha[j] = (_Float16)a[j]; hb[j] = (_Float16)b[j]; }
        ((half4v*)os)[i] = ha;
        ((half4v*)od)[i] = hb;
    }
}

// packed repack: cvt_pkrtz (2 f32 -> 2 f16) then lrelu in f16 (pk mul+max).
__device__ __forceinline__ half2v cvt_pk(float a, float b) {
    return __builtin_bit_cast(half2v, __builtin_amdgcn_cvt_pkrtz(a, b));
}

__device__ __forceinline__ half8 repack2(float4v lo, float4v hi) {
    half8 r;
#pragma unroll
    for (int j = 0; j < 2; ++j) {
        half2v a = cvt_pk(lo[2 * j], lo[2 * j + 1]);
        half2v sa = a * (_Float16)0.01f;
        half2v ma = __builtin_elementwise_max(a, sa);
        r[2 * j] = ma[0]; r[2 * j + 1] = ma[1];
        half2v b = cvt_pk(hi[2 * j], hi[2 * j + 1]);
        half2v sb = b * (_Float16)0.01f;
        half2v mb = __builtin_elementwise_max(b, sb);
        r[4 + 2 * j] = mb[0]; r[4 + 2 * j + 1] = mb[1];
    }
    return r;
}

// eidx prefetch: (src,dst) node index pair for this lane's edge of a tile
// (index clamp inside handles all overshoot)
__device__ __forceinline__ int2 load_eidx(const int* __restrict__ eidx,
                                          int nE, int tile, int n)
{
    int e = tile * 16 + n;
    int ec = e < nE ? e : nE - 1;
    return make_int2(eidx[ec], eidx[nE + ec]);
}

// R2-style consume gather from prefetched indices: lane (q,n) loads chunk q
// of edge n's 4 lines. Requests HIT L1/L2 (warmed iterations earlier).
__device__ __forceinline__ void gather_tile(const _Float16* __restrict__ xs,
                                            const _Float16* __restrict__ xd,
                                            int2 sd, int q, int4* G)
{
    const char* rs = (const char*)(xs + (size_t)sd.x * 64);
    const char* rd = (const char*)(xd + (size_t)sd.y * 64);
    G[0] = *(const int4*)(rs + 16 * q);
    G[1] = *(const int4*)(rs + 64 + 16 * q);
    G[2] = *(const int4*)(rd + 16 * q);
    G[3] = *(const int4*)(rd + 64 + 16 * q);
}

// warm pass from prefetched indices: lane (c=q, n) touches line (edge n,
// combo c) once -> 64 distinct lines per instruction, one 64B fill each.
__device__ __forceinline__ int4 warm_tile(const _Float16* __restrict__ xs,
                                          const _Float16* __restrict__ xd,
                                          int2 sd, int c)
{
    int idx = (c & 2) ? sd.y : sd.x;
    const char* base = (const char*)(((c & 2) ? xd : xs) + (size_t)idx * 64);
    return *(const int4*)(base + (c & 1) * 64);
}

__global__ __launch_bounds__(256, 2)
void edge_mlp_mfma(const unsigned char* __restrict__ ws,
                   const _Float16* __restrict__ xs, const _Float16* __restrict__ xd,
                   const int* __restrict__ eidx,
                   const float* __restrict__ eb4p, const float* __restrict__ wb4p,
                   float* __restrict__ out, int nE, int ntiles)
{
    __shared__ unsigned char lds[LDS_TOTAL];
    // stride-8 pairing: blocks 16k+j and 16k+8+j (j<8) run the same tiles for
    // m=0/1 -> same XCD (%8 preserved) and adjacent dispatch -> L2 dedup.
    const int m = (blockIdx.x >> 3) & 1;
    const int bid = (blockIdx.x & 7) | ((blockIdx.x >> 4) << 3);
    const unsigned char* wbase = ws + m * MLP_W_BYTES;
    const unsigned char* rbase = ws + WS_REST_OFF + m * MLP_R_BYTES;
    {
        const uint4* s = (const uint4*)(wbase + W1F);      // w1f|w2f|w3f contiguous
        uint4* d = (uint4*)lds;
        for (int i = threadIdx.x; i < 1792; i += 256) d[i] = s[i];
        const uint4* sb = (const uint4*)(rbase + 2048);     // b1f|b2f|b3f contiguous
        uint4* db = (uint4*)(lds + LB1F);
        for (int i = threadIdx.x; i < 640; i += 256) db[i] = sb[i];
    }

    const int lane = threadIdx.x & 63;
    const int q = lane >> 4, n = lane & 15;
    const int wid = (bid << 2) | (threadIdx.x >> 6);
    const int nwaves = gridDim.x << 1;     // (grid/2 blocks per MLP) * 4 waves
    const float b4s = m ? wb4p[0] : eb4p[0];
    float* __restrict__ outm = out + (m ? nE : 0);

    // ---- only w4 stays in registers (8) ----
    float4v w40 = *(const float4v*)(rbase + 0 + lane * 32);
    float4v w41 = *(const float4v*)(rbase + 0 + lane * 32 + 16);

    __syncthreads();

    int4 Gcur[4];
    int4 W0 = {0,0,0,0}, W1 = {0,0,0,0}, junk = {0,0,0,0};
    int2 I1 = {0,0}, I2 = {0,0}, I3 = {0,0};
    float4v accP[4];                       // L1 output of tile T
    float4v acc2P[4] = {{0,0,0,0},{0,0,0,0},{0,0,0,0},{0,0,0,0}};  // L2 of T-nw
    int prevValid = 0;

    int tile = wid;
    if (tile < ntiles) {
        int2 I0 = load_eidx(eidx, nE, tile, n);
        I1 = load_eidx(eidx, nE, tile + nwaves, n);
        I2 = load_eidx(eidx, nE, tile + 2 * nwaves, n);
        I3 = load_eidx(eidx, nE, tile + 3 * nwaves, n);
        // warm tiles t, t+1 (folded immediately; gathers queue behind fills)
        int4 ja = warm_tile(xs, xd, I0, q);
        int4 jb = warm_tile(xs, xd, I1, q);
        junk.x ^= ja.x ^ jb.x; junk.y ^= ja.y ^ jb.y;
        junk.z ^= ja.z ^ jb.z; junk.w ^= ja.w ^ jb.w;
        W0 = warm_tile(xs, xd, I2, q);
        W1 = warm_tile(xs, xd, I3, q);
        gather_tile(xs, xd, I0, q, Gcur);

        // ---- skew prologue: layer 1 for the first tile ----
        half8 B1[4];
#pragma unroll
        for (int s = 0; s < 4; ++s) B1[s] = __builtin_bit_cast(half8, Gcur[s]);
#pragma unroll
        for (int t = 0; t < 4; ++t) {
            accP[t] = *(const float4v*)(lds + LB1F + (t * 64 + lane) * 16);
#pragma unroll
            for (int s = 0; s < 4; ++s) {
                half8 A = *(const half8*)(lds + W1F + ((t * 4 + s) * 64 + lane) * 16);
                accP[t] = __builtin_amdgcn_mfma_f32_16x16x32_f16(A, B1[s], accP[t], 0, 0, 0);
            }
        }
        gather_tile(xs, xd, I1, q, Gcur);            // tile+1
        I1 = I2; I2 = I3;
        I3 = load_eidx(eidx, nE, tile + 4 * nwaves, n);
    }

#pragma unroll 1
    for (; tile < ntiles; tile += nwaves) {
        // B-operand for tile T+1 (gathered last iteration into Gcur)
        half8 B1n[4];
#pragma unroll
        for (int s = 0; s < 4; ++s) B1n[s] = __builtin_bit_cast(half8, Gcur[s]);

        __builtin_amdgcn_s_setprio(1);
        // ---- stream A: layer 1 of tile T+1 (independent) ----
        float4v accN[4];
#pragma unroll
        for (int t = 0; t < 4; ++t) {
            accN[t] = *(const float4v*)(lds + LB1F + (t * 64 + lane) * 16);
#pragma unroll
            for (int s = 0; s < 4; ++s) {
                half8 A = *(const half8*)(lds + W1F + ((t * 4 + s) * 64 + lane) * 16);
                accN[t] = __builtin_amdgcn_mfma_f32_16x16x32_f16(A, B1n[s], accN[t], 0, 0, 0);
            }
        }

        // ---- stream B: layer 2 of tile T (from accP) ----
        half8 B2[2] = { repack2(accP[0], accP[2]), repack2(accP[1], accP[3]) };
        float4v acc2N[4];
#pragma unroll
        for (int t = 0; t < 4; ++t) {
            acc2N[t] = *(const float4v*)(lds + LB2F + (t * 64 + lane) * 16);
#pragma unroll
            for (int s = 0; s < 2; ++s) {
                half8 A = *(const half8*)(lds + W2F + ((t * 2 + s) * 64 + lane) * 16);
                acc2N[t] = __builtin_amdgcn_mfma_f32_16x16x32_f16(A, B2[s], acc2N[t], 0, 0, 0);
            }
        }

        // ---- stream C: layers 3-4 of tile T-nw (acc2P; zeros on iter 0) ----
        half8 B3[2] = { repack2(acc2P[0], acc2P[2]), repack2(acc2P[1], acc2P[3]) };
        float4v acc3[2];
#pragma unroll
        for (int t = 0; t < 2; ++t) {
            acc3[t] = *(const float4v*)(lds + LB3F + (t * 64 + lane) * 16);
#pragma unroll
            for (int s = 0; s < 2; ++s) {
                half8 A = *(const half8*)(lds + W3F + ((t * 2 + s) * 64 + lane) * 16);
                acc3[t] = __builtin_amdgcn_mfma_f32_16x16x32_f16(A, B3[s], acc3[t], 0, 0, 0);
            }
        }
        float o = 0.f;
#pragma unroll
        for (int r = 0; r < 4; ++r) o = fmaf(lrelu(acc3[0][r]), w40[r], o);
#pragma unroll
        for (int r = 0; r < 4; ++r) o = fmaf(lrelu(acc3[1][r]), w41[r], o);
        o += __shfl_xor(o, 16, 64);
        o += __shfl_xor(o, 32, 64);
        __builtin_amdgcn_s_setprio(0);

        // ---- memory-issue block (low prio; unchanged schedule) ----
        // Gcur dead (B1n cast) -> gather tile T+2 in place; lines warmed
        // 2 iterations ago (~15K cyc >> 900cy fill) -> L1/L2 hits.
        gather_tile(xs, xd, I1, q, Gcur);
        // fold warm(T+2) (issued 2 iters ago), shift, issue warm(T+4)
        junk.x ^= W0.x; junk.y ^= W0.y; junk.z ^= W0.z; junk.w ^= W0.w;
        W0 = W1;
        W1 = warm_tile(xs, xd, I3, q);
        // rotate eidx; fetch idx(T+5)
        I1 = I2; I2 = I3;
        I3 = load_eidx(eidx, nE, tile + 5 * nwaves, n);

        // store tile T-nw's result (delayed by one iteration)
        int eprev = (tile - nwaves) * 16 + n;
        if (prevValid && q == 0 && eprev < nE)
            outm[eprev] = o + b4s;
        prevValid = 1;

#pragma unroll
        for (int t = 0; t < 4; ++t) { accP[t] = accN[t]; acc2P[t] = acc2N[t]; }
    }

    // ---- epilogue flush: layers 3-4 + store for the last tile ----
    if (wid < ntiles && prevValid) {
        half8 B3[2] = { repack2(acc2P[0], acc2P[2]), repack2(acc2P[1], acc2P[3]) };
        float4v acc3[2];
#pragma unroll
        for (int t = 0; t < 2; ++t) {
            acc3[t] = *(const float4v*)(lds + LB3F + (t * 64 + lane) * 16);
#pragma unroll
            for (int s = 0; s < 2; ++s) {
                half8 A = *(const half8*)(lds + W3F + ((t * 2 + s) * 64 + lane) * 16);
                acc3[t] = __builtin_amdgcn_mfma_f32_16x16x32_f16(A, B3[s], acc3[t], 0, 0, 0);
            }
        }
        float o = 0.f;
#pragma unroll
        for (int r = 0; r < 4; ++r) o = fmaf(lrelu(acc3[0][r]), w40[r], o);
#pragma unroll
        for (int r = 0; r < 4; ++r) o = fmaf(lrelu(acc3[1][r]), w41[r], o);
        o += __shfl_xor(o, 16, 64);
        o += __shfl_xor(o, 32, 64);
        int elast = (tile - nwaves) * 16 + n;
        if (q == 0 && elast < nE)
            outm[elast] = o + b4s;
    }

    // consume warm registers (never-taken, data-dependent guard defeats DCE)
    junk.x ^= W0.x ^ W1.x;
    junk.y ^= W0.y ^ W1.y;
    junk.z ^= W0.z ^ W1.z;
    junk.w ^= W0.w ^ W1.w;
    if (nE < 0 && (junk.x | junk.y | junk.z | junk.w) != 0)
        out[0] = -1.0f;
}

extern "C" void kernel_launch(void* const* d_in, const int* in_sizes, int n_in,
                              void* d_out, int out_size, void* d_ws, size_t ws_size,
                              hipStream_t stream)
{
    const float* x_src = (const float*)d_in[0];
    const float* x_dst = (const float*)d_in[1];
    const int*   eidx  = (const int*)d_in[2];
    const float* ew1 = (const float*)d_in[3];
    const float* eb1 = (const float*)d_in[4];
    const float* ww1 = (const float*)d_in[5];
    const float* wb1 = (const float*)d_in[6];
    const float* ew2 = (const float*)d_in[7];
    const float* eb2 = (const float*)d_in[8];
    const float* ww2 = (const float*)d_in[9];
    const float* wb2 = (const float*)d_in[10];
    const float* ew3 = (const float*)d_in[11];
    const float* eb3 = (const float*)d_in[12];
    const float* ww3 = (const float*)d_in[13];
    const float* wb3 = (const float*)d_in[14];
    const float* ew4 = (const float*)d_in[15];
    const float* eb4 = (const float*)d_in[16];
    const float* ww4 = (const float*)d_in[17];
    const float* wb4 = (const float*)d_in[18];
    float* out = (float*)d_out;

    const int nE = in_sizes[2] / 2;          // 2 x E index array (int32)
    const int nNodeElems = in_sizes[0];      // N_NODES * 64
    unsigned char* ws = (unsigned char*)d_ws;
    _Float16* xs16 = (_Float16*)(ws + WS_X16_OFF);
    _Float16* xd16 = xs16 + nNodeElems;

    prep_frags<<<68, 256, 0, stream>>>(ew1, eb1, ew2, eb2, ew3, eb3, ew4,
                                       ws, ws + WS_REST_OFF);
    prep_frags<<<68, 256, 0, stream>>>(ww1, wb1, ww2, wb2, ww3, wb3, ww4,
                                       ws + MLP_W_BYTES, ws + WS_REST_OFF + MLP_R_BYTES);
    prep_nodes<<<1024, 256, 0, stream>>>(x_src, x_dst, xs16, xd16, nNodeElems / 4);

    const int ntiles = (nE + 15) / 16;
    // grid 512: exactly resident at 2 blocks/CU (reg-tier bound) -> one
    // block-round, no second wave of cold prologues.
    edge_mlp_mfma<<<512, 256, 0, stream>>>(ws, xs16, xd16, eidx, eb4, wb4,
                                           out, nE, ntiles);
}